// Round 3
// baseline (115.023 us; speedup 1.0000x reference)
//
#include <hip/hip_runtime.h>
#include <math.h>

// y[b,f,t] = | x[t] - C_f*w_f * S[t] |,  S[t] = sum_{j=0}^{497} a^j x[t-1-j] (edge-padded)
//
// R6 = R5 + LDS XOR-swizzle. All R5 LDS traffic had lane-stride 32B:
//   - lag reads (8x ds_read_b32, dword-stride 8): 16-way bank conflict
//   - stage writes / warm-up reads (b128 @ 32B stride): 2x over minimum
// swz(i) = i ^ (((i>>5)&7)<<2) XORs row bits into the bank-group bits
// (float4-granular: bits [1:0] untouched -> b128/b64 contiguity + 16B
// alignment preserved; involution; stays within the 8K-float buffer).
// Verified per-pattern: b128 stage/warm -> 8 lanes/bank-group (= 8-round
// minimum); lag reads -> 2 lanes/bank (free). Math identical to R5.

constexpr int T     = 8000;
constexpr int F     = 64;
constexpr int B     = 32;
constexpr int KM1   = 498;
constexpr int CHUNK = 512;                       // samples per wave (8/lane)
constexpr int CPR   = 16;                        // chunks (waves) per row

#define DPP_F(x, ctrl, rm) \
  __builtin_bit_cast(float, __builtin_amdgcn_update_dpp(0, __builtin_bit_cast(int, (x)), (ctrl), (rm), 0xf, false))

__device__ __forceinline__ double dpow(double b, int e) {
    double r = 1.0, p = b;
    while (e) { if (e & 1) r *= p; p *= p; e >>= 1; }
    return r;
}

// branch-free float base^e, e in [0, 512)
__device__ __forceinline__ float powi(float base, int e) {
    float r = 1.0f, p = base;
    #pragma unroll
    for (int b = 0; b < 9; ++b) { r = (e & (1 << b)) ? r * p : r; p *= p; }
    return r;
}

// LDS bank swizzle, float-index domain, float4-granular.
__device__ __forceinline__ int swz(int i) { return i ^ (((i >> 5) & 7) << 2); }

__global__ __launch_bounds__(1024, 1) void willmore_scan_kernel(
    const float* __restrict__ x, const float* __restrict__ a,
    const float* __restrict__ w, float* __restrict__ out)
{
    __shared__ float lx[CPR * CHUNK];    // 32 KB: the whole row, staged once

    const int chunk = threadIdx.x >> 6;  // 0..15, one wave per chunk
    const int lane  = threadIdx.x & 63;
    const int row   = blockIdx.x;        // b*F + f
    const int f     = row & (F - 1);

    const float* xr   = x   + (size_t)row * T;
    float*       orow = out + (size_t)row * T;

    const int t0   = chunk * CHUNK;
    const int tb_u = t0 + 8 * lane;          // unclamped output base
    const int tb   = min(tb_u, T - 8);       // clamp bites only in chunk 15

    // ---- issue the (only) global loads up front ----
    const float4 m0 = *(const float4*)(xr + tb);
    const float4 m1 = *(const float4*)(xr + tb + 4);

    // ---- per-row constants, computed while loads are in flight ----
    const double ad     = (double)a[f];
    const double a498d  = dpow(ad, KM1);
    const double sumgeo = (1.0 - a498d) / (1.0 - ad);
    const double r_d    = dpow(ad, 8);
    const float  af     = (float)ad;
    const float  na498  = (float)(-a498d);
    const float  g      = (float)(1.0 / sumgeo) * w[f];
    const float  r1     = (float)r_d;
    const float  r2     = (float)(r_d * r_d);
    const float  r4     = (float)dpow(r_d, 4);
    const float  r8     = (float)dpow(r_d, 8);
    const float  inv_r  = (float)(1.0 / r_d);
    const float  alane  = powi(af, 8 * lane);                  // a^(8*lane)
    const float  wA     = powi(af, 8 * ((lane & 15) + 1));     // bcast15 weight
    const float  wB     = powi(af, 8 * ((lane & 31) + 1));     // bcast31 weight

    // ---- stage to LDS, swizzled (chunk-15 clamped lanes duplicate: benign) ----
    *(float4*)(&lx[swz(tb)])     = m0;
    *(float4*)(&lx[swz(tb + 4)]) = m1;
    __syncthreads();

    // ---- warm-up: S = S[t0] = sum_{j=0}^{497} a^j x[t0-1-j], from LDS ----
    float S;
    if (chunk == 0) {
        S = lx[0] * (float)sumgeo;           // swz(0)==0; broadcast read
    } else {
        const int wb = t0 - CHUNK + 8 * lane;        // [t0-512, t0)
        const float4 w0 = *(const float4*)(&lx[swz(wb)]);
        const float4 w1 = *(const float4*)(&lx[swz(wb + 4)]);
        float ws8[8] = {w0.x, w0.y, w0.z, w0.w, w1.x, w1.y, w1.z, w1.w};
        // idx = t0-512+8*lane+i has j = 511-8*lane-i; drop j>497 (8*lane+i<14)
        #pragma unroll
        for (int i = 0; i < 8; ++i) { if (8 * lane + i < 14) ws8[i] = 0.0f; }
        float h = ws8[0];
        #pragma unroll
        for (int i = 1; i < 8; ++i) h = fmaf(h, af, ws8[i]);
        float contrib = powi(af, 504 - 8 * lane) * h;
        #pragma unroll
        for (int s = 1; s < 64; s <<= 1) contrib += __shfl_xor(contrib, s, 64);
        S = contrib;
    }

    // ---- lag window x[tb-498 .. tb-491] from LDS (edge-pad clamps to x[0]) ----
    // lg is even and lg mod 4 == 2: float2 pairs never straddle a float4, so
    // swizzled float2 reads are contiguous & 8B-aligned. Chunk 0 needs the
    // per-element clamp -> scalar path (wave-uniform branch).
    const int lg = tb - KM1;
    float lv[8];
    if (chunk == 0) {
        #pragma unroll
        for (int i = 0; i < 8; ++i) lv[i] = lx[swz(max(lg + i, 0))];
    } else {
        #pragma unroll
        for (int i = 0; i < 4; ++i) {
            const float2 p = *(const float2*)(&lx[swz(lg + 2 * i)]);
            lv[2 * i]     = p.x;
            lv[2 * i + 1] = p.y;
        }
    }

    // ---- main: u, lane aggregate, DPP weighted scan (ratio a^8) ----
    const float xv[8] = {m0.x, m0.y, m0.z, m0.w, m1.x, m1.y, m1.z, m1.w};
    float u[8];
    #pragma unroll
    for (int i = 0; i < 8; ++i) u[i] = fmaf(na498, lv[i], xv[i]);

    float q = u[0];
    #pragma unroll
    for (int i = 1; i < 8; ++i) q = fmaf(q, af, u[i]);

    float G = q;
    G = fmaf(r1, DPP_F(G, 0x111, 0xf), G);   // row_shr:1
    G = fmaf(r2, DPP_F(G, 0x112, 0xf), G);   // row_shr:2
    G = fmaf(r4, DPP_F(G, 0x114, 0xf), G);   // row_shr:4
    G = fmaf(r8, DPP_F(G, 0x118, 0xf), G);   // row_shr:8
    G = fmaf(wA, DPP_F(G, 0x142, 0xa), G);   // row_bcast15 -> rows 1,3
    G = fmaf(wB, DPP_F(G, 0x143, 0xc), G);   // row_bcast31 -> rows 2,3

    const float E = (G - q) * inv_r;         // exclusive prefix (exact 0 at lane 0)

    float s = fmaf(alane, S, E);             // S[t0 + 8*lane]
    float y[8];
    #pragma unroll
    for (int i = 0; i < 8; ++i) {
        y[i] = fabsf(fmaf(-g, s, xv[i]));
        s = fmaf(af, s, u[i]);
    }

    if (tb_u <= T - 8) {
        *(float4*)(orow + tb)     = make_float4(y[0], y[1], y[2], y[3]);
        *(float4*)(orow + tb + 4) = make_float4(y[4], y[5], y[6], y[7]);
    }
}

extern "C" void kernel_launch(void* const* d_in, const int* in_sizes, int n_in,
                              void* d_out, int out_size, void* d_ws, size_t ws_size,
                              hipStream_t stream) {
    const float* x = (const float*)d_in[0];
    const float* a = (const float*)d_in[1];
    const float* w = (const float*)d_in[2];
    float* out = (float*)d_out;

    // one block per (b,f) row: 2048 blocks x 16 waves
    hipLaunchKernelGGL(willmore_scan_kernel, dim3(B * F), dim3(1024), 0, stream,
                       x, a, w, out);
}

// Round 4
// 113.176 us; speedup vs baseline: 1.0163x; 1.0163x over previous
//
#include <hip/hip_runtime.h>
#include <math.h>

// y[b,f,t] = | x[t] - C_f*w_f * S[t] |,  S[t] = sum_{j=0}^{497} a^j x[t-1-j] (edge-padded)
//
// R7: residency/overlap fix. R6's 1024-thr block = 16 waves = only resident
// block on its CU (VGPR>64) -> the staging barrier stalls the whole CU and
// block k+1's loads can't overlap block k's store drain. Now: 512-thr block
// per HALF-row (4096 samples, 18KB LDS incl. 512-float halo re-fetched from
// global by second-half blocks, +1.5% traffic). Per-row f64 constants are
// computed once by thread 0 and LDS-broadcast (bit-identical; kills ~500cy
// of redundant per-wave VALU). __launch_bounds__(512,4) -> >=2 blocks/CU.
// Math identical to R6 (absmax must stay 0.00390625).

constexpr int T     = 8000;
constexpr int F     = 64;
constexpr int B     = 32;
constexpr int KM1   = 498;
constexpr int CHUNK = 512;                 // samples per wave (8/lane)
constexpr int HALF  = 4096;                // samples per block
constexpr int LXN   = HALF + CHUNK;        // halo + half-row, 18KB

#define DPP_F(x, ctrl, rm) \
  __builtin_bit_cast(float, __builtin_amdgcn_update_dpp(0, __builtin_bit_cast(int, (x)), (ctrl), (rm), 0xf, false))

__device__ __forceinline__ double dpow(double b, int e) {
    double r = 1.0, p = b;
    while (e) { if (e & 1) r *= p; p *= p; e >>= 1; }
    return r;
}

// branch-free float base^e, e in [0, 512)
__device__ __forceinline__ float powi(float base, int e) {
    float r = 1.0f, p = base;
    #pragma unroll
    for (int b = 0; b < 9; ++b) { r = (e & (1 << b)) ? r * p : r; p *= p; }
    return r;
}

// LDS bank swizzle, float-index domain, float4-granular (involution).
__device__ __forceinline__ int swz(int i) { return i ^ (((i >> 5) & 7) << 2); }

__global__ __launch_bounds__(512, 4) void willmore_scan_kernel(
    const float* __restrict__ x, const float* __restrict__ a,
    const float* __restrict__ w, float* __restrict__ out)
{
    __shared__ float lx[LXN];   // [0,512): halo, [512,4608): half-row
    __shared__ float cb[8];     // 0:na498 1:g 2:r1 3:r2 4:r4 5:r8 6:inv_r 7:sumgeo

    const int tid  = threadIdx.x;
    const int cl   = tid >> 6;            // chunk-local 0..7 (one wave each)
    const int lane = tid & 63;
    const int row  = blockIdx.x >> 1;     // b*F + f
    const int half = blockIdx.x & 1;
    const int f    = row & (F - 1);
    const int h0   = half * HALF;

    const float* xr   = x   + (size_t)row * T;
    float*       orow = out + (size_t)row * T;

    const int t0   = h0 + cl * CHUNK;
    const int tb_u = t0 + 8 * lane;          // unclamped output base
    const int tb   = min(tb_u, T - 8);       // clamp bites only in last chunk
    const int lb   = tb - h0 + CHUNK;        // LDS index of tb

    // ---- issue ALL global loads up front ----
    const float4 m0 = *(const float4*)(xr + tb);
    const float4 m1 = *(const float4*)(xr + tb + 4);
    float4 hv;
    if (half && tid < 128)                    // halo x[h0-512 .. h0)
        hv = *(const float4*)(xr + h0 - CHUNK + 4 * tid);

    // ---- per-lane f32 constants (every thread; overlaps loads) ----
    const float af    = a[f];
    const float alane = powi(af, 8 * lane);                  // a^(8*lane)
    const float wA    = powi(af, 8 * ((lane & 15) + 1));     // bcast15 weight
    const float wB    = powi(af, 8 * ((lane & 31) + 1));     // bcast31 weight

    // ---- per-row f64 constants: thread 0 only, broadcast via LDS ----
    if (tid == 0) {
        const double ad     = (double)af;
        const double a498d  = dpow(ad, KM1);
        const double sumgeo = (1.0 - a498d) / (1.0 - ad);
        const double r_d    = dpow(ad, 8);
        cb[0] = (float)(-a498d);
        cb[1] = (float)(1.0 / sumgeo) * w[f];
        cb[2] = (float)r_d;
        cb[3] = (float)(r_d * r_d);
        cb[4] = (float)dpow(r_d, 4);
        cb[5] = (float)dpow(r_d, 8);
        cb[6] = (float)(1.0 / r_d);
        cb[7] = (float)sumgeo;
    }

    // ---- stage to LDS (clamped lanes duplicate identical values: benign) ----
    *(float4*)(&lx[swz(lb)])     = m0;
    *(float4*)(&lx[swz(lb + 4)]) = m1;
    if (half && tid < 128)
        *(float4*)(&lx[swz(4 * tid)]) = hv;
    __syncthreads();

    const float na498 = cb[0], g  = cb[1], r1    = cb[2], r2 = cb[3],
                r4    = cb[4], r8 = cb[5], inv_r = cb[6];

    // ---- warm-up: S = S[t0] = sum_{j=0}^{497} a^j x[t0-1-j] ----
    float S;
    if (half == 0 && cl == 0) {
        S = lx[swz(CHUNK)] * cb[7];          // x[0] * sumgeo (edge-pad closed form)
    } else {
        const int wl = cl * CHUNK + 8 * lane;        // LDS idx of [t0-512, t0)
        const float4 w0 = *(const float4*)(&lx[swz(wl)]);
        const float4 w1 = *(const float4*)(&lx[swz(wl + 4)]);
        float ws8[8] = {w0.x, w0.y, w0.z, w0.w, w1.x, w1.y, w1.z, w1.w};
        // idx = t0-512+8*lane+i has j = 511-8*lane-i; drop j>497 (8*lane+i<14)
        #pragma unroll
        for (int i = 0; i < 8; ++i) { if (8 * lane + i < 14) ws8[i] = 0.0f; }
        float h = ws8[0];
        #pragma unroll
        for (int i = 1; i < 8; ++i) h = fmaf(h, af, ws8[i]);
        float contrib = powi(af, 504 - 8 * lane) * h;
        #pragma unroll
        for (int s = 1; s < 64; s <<= 1) contrib += __shfl_xor(contrib, s, 64);
        S = contrib;
    }

    // ---- lag window x[tb-498 .. tb-491] (edge-pad clamps to x[0]) ----
    // LDS idx = lg - h0 + 512 ≡ 2 (mod 4): float2 pairs never straddle a
    // float4, so swizzled float2 reads stay contiguous & 8B-aligned.
    const int lg = tb - KM1;
    float lv[8];
    if (half == 0 && cl == 0) {
        #pragma unroll
        for (int i = 0; i < 8; ++i) lv[i] = lx[swz(max(lg + i, 0) + CHUNK)];
    } else {
        const int ll = lg - h0 + CHUNK;
        #pragma unroll
        for (int i = 0; i < 4; ++i) {
            const float2 p = *(const float2*)(&lx[swz(ll + 2 * i)]);
            lv[2 * i]     = p.x;
            lv[2 * i + 1] = p.y;
        }
    }

    // ---- main: u, lane aggregate, DPP weighted scan (ratio a^8) ----
    const float xv[8] = {m0.x, m0.y, m0.z, m0.w, m1.x, m1.y, m1.z, m1.w};
    float u[8];
    #pragma unroll
    for (int i = 0; i < 8; ++i) u[i] = fmaf(na498, lv[i], xv[i]);

    float q = u[0];
    #pragma unroll
    for (int i = 1; i < 8; ++i) q = fmaf(q, af, u[i]);

    float G = q;
    G = fmaf(r1, DPP_F(G, 0x111, 0xf), G);   // row_shr:1
    G = fmaf(r2, DPP_F(G, 0x112, 0xf), G);   // row_shr:2
    G = fmaf(r4, DPP_F(G, 0x114, 0xf), G);   // row_shr:4
    G = fmaf(r8, DPP_F(G, 0x118, 0xf), G);   // row_shr:8
    G = fmaf(wA, DPP_F(G, 0x142, 0xa), G);   // row_bcast15 -> rows 1,3
    G = fmaf(wB, DPP_F(G, 0x143, 0xc), G);   // row_bcast31 -> rows 2,3

    const float E = (G - q) * inv_r;         // exclusive prefix (exact 0 at lane 0)

    float s = fmaf(alane, S, E);             // S[t0 + 8*lane]
    float y[8];
    #pragma unroll
    for (int i = 0; i < 8; ++i) {
        y[i] = fabsf(fmaf(-g, s, xv[i]));
        s = fmaf(af, s, u[i]);
    }

    if (tb_u <= T - 8) {
        *(float4*)(orow + tb)     = make_float4(y[0], y[1], y[2], y[3]);
        *(float4*)(orow + tb + 4) = make_float4(y[4], y[5], y[6], y[7]);
    }
}

extern "C" void kernel_launch(void* const* d_in, const int* in_sizes, int n_in,
                              void* d_out, int out_size, void* d_ws, size_t ws_size,
                              hipStream_t stream) {
    const float* x = (const float*)d_in[0];
    const float* a = (const float*)d_in[1];
    const float* w = (const float*)d_in[2];
    float* out = (float*)d_out;

    // one block per half-row: 4096 blocks x 8 waves
    hipLaunchKernelGGL(willmore_scan_kernel, dim3(B * F * 2), dim3(512), 0, stream,
                       x, a, w, out);
}

// Round 6
// 112.500 us; speedup vs baseline: 1.0224x; 1.0060x over previous
//
#include <hip/hip_runtime.h>
#include <math.h>

// y[b,f,t] = | x[t] - C_f*w_f * S[t] |,  S[t] = sum_{j=0}^{497} a^j x[t-1-j] (edge-padded)
//
// R9 = R8 with the nontemporal-store compile fix (__builtin_nontemporal_store
// needs a native clang vector type, not HIP's float4 class).
// R8 theory: 256-thr quarter-row blocks (10KB LDS, ~6 resident/CU via
// launch_bounds(256,6)) -> fine-grained phase interleave; XCD swizzle keeps
// a row's quarters on one XCD so the 512-float halo re-fetch is L2-local;
// nontemporal stores keep the write stream from evicting x in L2.
// Math identical to R7 (absmax must stay 0.00390625).

constexpr int T     = 8000;
constexpr int F     = 64;
constexpr int B     = 32;
constexpr int KM1   = 498;
constexpr int CHUNK = 512;                 // samples per wave (8/lane)
constexpr int QUART = 2048;                // samples per block (4 waves)
constexpr int LXN   = QUART + CHUNK;       // halo + quarter, 10KB

typedef float vfloat4 __attribute__((ext_vector_type(4)));

#define DPP_F(x, ctrl, rm) \
  __builtin_bit_cast(float, __builtin_amdgcn_update_dpp(0, __builtin_bit_cast(int, (x)), (ctrl), (rm), 0xf, false))

__device__ __forceinline__ double dpow(double b, int e) {
    double r = 1.0, p = b;
    while (e) { if (e & 1) r *= p; p *= p; e >>= 1; }
    return r;
}

// branch-free float base^e, e in [0, 512)
__device__ __forceinline__ float powi(float base, int e) {
    float r = 1.0f, p = base;
    #pragma unroll
    for (int b = 0; b < 9; ++b) { r = (e & (1 << b)) ? r * p : r; p *= p; }
    return r;
}

// LDS bank swizzle, float-index domain, float4-granular (involution).
__device__ __forceinline__ int swz(int i) { return i ^ (((i >> 5) & 7) << 2); }

__global__ __launch_bounds__(256, 6) void willmore_scan_kernel(
    const float* __restrict__ x, const float* __restrict__ a,
    const float* __restrict__ w, float* __restrict__ out)
{
    __shared__ float lx[LXN];   // [0,512): halo, [512,2560): quarter-row
    __shared__ float cb[8];     // 0:na498 1:g 2:r1 3:r2 4:r4 5:r8 6:inv_r 7:sumgeo

    // XCD-aware swizzle: 8192 blocks, 8 XCDs, 8192%8==0 -> bijective.
    // Consecutive quarters of a row land on the same XCD -> halo is L2-local.
    const int bid  = blockIdx.x;
    const int qid  = ((bid & 7) << 10) | (bid >> 3);

    const int tid  = threadIdx.x;
    const int cl   = tid >> 6;            // chunk-local 0..3 (one wave each)
    const int lane = tid & 63;
    const int row  = qid >> 2;            // b*F + f
    const int qpos = qid & 3;
    const int f    = row & (F - 1);
    const int q0   = qpos * QUART;

    const float* xr   = x   + (size_t)row * T;
    float*       orow = out + (size_t)row * T;

    const int t0   = q0 + cl * CHUNK;
    const int tb_u = t0 + 8 * lane;          // unclamped output base
    const int tb   = min(tb_u, T - 8);       // clamps only in last chunk of row
    const int lb   = tb - q0 + CHUNK;        // LDS index of tb

    // ---- issue ALL global loads up front ----
    const float4 m0 = *(const float4*)(xr + tb);
    const float4 m1 = *(const float4*)(xr + tb + 4);
    float4 hv;
    if (qpos && tid < 128)                    // halo x[q0-512 .. q0)
        hv = *(const float4*)(xr + q0 - CHUNK + 4 * tid);

    // ---- per-lane f32 constants (every thread; overlaps loads) ----
    const float af    = a[f];
    const float alane = powi(af, 8 * lane);                  // a^(8*lane)
    const float wA    = powi(af, 8 * ((lane & 15) + 1));     // bcast15 weight
    const float wB    = powi(af, 8 * ((lane & 31) + 1));     // bcast31 weight

    // ---- per-row f64 constants: thread 0 only, broadcast via LDS ----
    if (tid == 0) {
        const double ad     = (double)af;
        const double a498d  = dpow(ad, KM1);
        const double sumgeo = (1.0 - a498d) / (1.0 - ad);
        const double r_d    = dpow(ad, 8);
        cb[0] = (float)(-a498d);
        cb[1] = (float)(1.0 / sumgeo) * w[f];
        cb[2] = (float)r_d;
        cb[3] = (float)(r_d * r_d);
        cb[4] = (float)dpow(r_d, 4);
        cb[5] = (float)dpow(r_d, 8);
        cb[6] = (float)(1.0 / r_d);
        cb[7] = (float)sumgeo;
    }

    // ---- stage to LDS (clamped lanes duplicate identical values: benign) ----
    *(float4*)(&lx[swz(lb)])     = m0;
    *(float4*)(&lx[swz(lb + 4)]) = m1;
    if (qpos && tid < 128)
        *(float4*)(&lx[swz(4 * tid)]) = hv;
    __syncthreads();

    const float na498 = cb[0], g  = cb[1], r1    = cb[2], r2 = cb[3],
                r4    = cb[4], r8 = cb[5], inv_r = cb[6];

    // ---- warm-up: S = S[t0] = sum_{j=0}^{497} a^j x[t0-1-j] ----
    float S;
    if (qpos == 0 && cl == 0) {
        S = lx[swz(CHUNK)] * cb[7];          // x[0] * sumgeo (edge-pad closed form)
    } else {
        const int wl = cl * CHUNK + 8 * lane;        // LDS idx of [t0-512, t0)
        const float4 w0 = *(const float4*)(&lx[swz(wl)]);
        const float4 w1 = *(const float4*)(&lx[swz(wl + 4)]);
        float ws8[8] = {w0.x, w0.y, w0.z, w0.w, w1.x, w1.y, w1.z, w1.w};
        // idx = t0-512+8*lane+i has j = 511-8*lane-i; drop j>497 (8*lane+i<14)
        #pragma unroll
        for (int i = 0; i < 8; ++i) { if (8 * lane + i < 14) ws8[i] = 0.0f; }
        float h = ws8[0];
        #pragma unroll
        for (int i = 1; i < 8; ++i) h = fmaf(h, af, ws8[i]);
        float contrib = powi(af, 504 - 8 * lane) * h;
        #pragma unroll
        for (int s = 1; s < 64; s <<= 1) contrib += __shfl_xor(contrib, s, 64);
        S = contrib;
    }

    // ---- lag window x[tb-498 .. tb-491] (edge-pad clamps to x[0]) ----
    // LDS idx = lg - q0 + 512 ≡ 2 (mod 4): float2 pairs never straddle a
    // float4, so swizzled float2 reads stay contiguous & 8B-aligned.
    const int lg = tb - KM1;
    float lv[8];
    if (qpos == 0 && cl == 0) {
        #pragma unroll
        for (int i = 0; i < 8; ++i) lv[i] = lx[swz(max(lg + i, 0) + CHUNK)];
    } else {
        const int ll = lg - q0 + CHUNK;
        #pragma unroll
        for (int i = 0; i < 4; ++i) {
            const float2 p = *(const float2*)(&lx[swz(ll + 2 * i)]);
            lv[2 * i]     = p.x;
            lv[2 * i + 1] = p.y;
        }
    }

    // ---- main: u, lane aggregate, DPP weighted scan (ratio a^8) ----
    const float xv[8] = {m0.x, m0.y, m0.z, m0.w, m1.x, m1.y, m1.z, m1.w};
    float u[8];
    #pragma unroll
    for (int i = 0; i < 8; ++i) u[i] = fmaf(na498, lv[i], xv[i]);

    float q = u[0];
    #pragma unroll
    for (int i = 1; i < 8; ++i) q = fmaf(q, af, u[i]);

    float G = q;
    G = fmaf(r1, DPP_F(G, 0x111, 0xf), G);   // row_shr:1
    G = fmaf(r2, DPP_F(G, 0x112, 0xf), G);   // row_shr:2
    G = fmaf(r4, DPP_F(G, 0x114, 0xf), G);   // row_shr:4
    G = fmaf(r8, DPP_F(G, 0x118, 0xf), G);   // row_shr:8
    G = fmaf(wA, DPP_F(G, 0x142, 0xa), G);   // row_bcast15 -> rows 1,3
    G = fmaf(wB, DPP_F(G, 0x143, 0xc), G);   // row_bcast31 -> rows 2,3

    const float E = (G - q) * inv_r;         // exclusive prefix (exact 0 at lane 0)

    float s = fmaf(alane, S, E);             // S[t0 + 8*lane]
    float y[8];
    #pragma unroll
    for (int i = 0; i < 8; ++i) {
        y[i] = fabsf(fmaf(-g, s, xv[i]));
        s = fmaf(af, s, u[i]);
    }

    if (tb_u <= T - 8) {
        const vfloat4 o0 = {y[0], y[1], y[2], y[3]};
        const vfloat4 o1 = {y[4], y[5], y[6], y[7]};
        __builtin_nontemporal_store(o0, (vfloat4*)(orow + tb));
        __builtin_nontemporal_store(o1, (vfloat4*)(orow + tb + 4));
    }
}

extern "C" void kernel_launch(void* const* d_in, const int* in_sizes, int n_in,
                              void* d_out, int out_size, void* d_ws, size_t ws_size,
                              hipStream_t stream) {
    const float* x = (const float*)d_in[0];
    const float* a = (const float*)d_in[1];
    const float* w = (const float*)d_in[2];
    float* out = (float*)d_out;

    // one block per quarter-row: 8192 blocks x 4 waves
    hipLaunchKernelGGL(willmore_scan_kernel, dim3(B * F * 4), dim3(256), 0, stream,
                       x, a, w, out);
}